// Round 6
// baseline (70.476 us; speedup 1.0000x reference)
//
#include <hip/hip_runtime.h>
#include <math.h>

#define B_DIM 4
#define N_DIM 8192
#define C_DIM 256
#define LN_EPS 1e-5f
#define WSCALE 4096.0f
#define INV_WSCALE (1.0f/4096.0f)
#define SUM_SCALE 8192.0f
#define INV_SUM_SCALE (1.0f/8192.0f)
#define M_SCALE 67108864.0f        // 2^26
#define INV_M_SCALE (1.0f/67108864.0f)

typedef _Float16 f16x8 __attribute__((ext_vector_type(8)));
typedef float    f32x4 __attribute__((ext_vector_type(4)));

// ---- workspace layout (bytes) ----
#define WS_WT    0          // 33 n-tiles x 8 kt x 64 lanes x 16B f16 fragments = 270336
#define WS_K1    270336     // K1h[8]
#define WS_K2    270400     // K2h[8]
#define WS_PART  270464     // part[1024][256] f32 = 1 MB
#define WS_QK    1319040    // qk[4][256] f32

// ---------------------------------------------------------------------------
// k0: pack all B-fragments. grid 33, block nt<32 packs Wk/Wv 16-col tile;
// block nt==32 computes the ext tile in-LDS (M[k,h]*2^26, row-sums*2^13)
// plus K1h/K2h, then packs it. B-frag (16x16x32): lane l holds B[k][n],
// n = nt*16+(l&15), k = kt*32+(l>>4)*8+j.
// ---------------------------------------------------------------------------
__global__ void k0_pack(const float* __restrict__ Wq,
                        const float* __restrict__ Wk,
                        const float* __restrict__ Wv,
                        const float* __restrict__ gamma,
                        const float* __restrict__ beta,
                        char* __restrict__ ws)
{
    __shared__ float Wl[256 * 16];
    const int t  = threadIdx.x;
    const int nt = blockIdx.x;

    if (nt == 32) {
        const int k = t;
        const float* __restrict__ wkrow = Wk + (size_t)k * C_DIM;
        const float* __restrict__ wvrow = Wv + (size_t)k * C_DIM;
        float pks = 0.f, pvs = 0.f;
        #pragma unroll
        for (int h = 0; h < 8; ++h) {
            float m = 0.f;
            #pragma unroll 8
            for (int d = 0; d < 32; ++d) {
                const int c = h * 32 + d;
                const float wg = Wq[c] * gamma[c];
                const float a  = wkrow[c];
                m = fmaf(a, wg, m);
                pks += a;
                pvs += wvrow[c];
            }
            Wl[k * 16 + h] = m * M_SCALE;
        }
        Wl[k * 16 + 8] = pks * SUM_SCALE;
        Wl[k * 16 + 9] = pvs * SUM_SCALE;
        #pragma unroll
        for (int j = 10; j < 16; ++j) Wl[k * 16 + j] = 0.f;

        if (t < 8) {
            float k1v = 0.f, k2v = 0.f;
            for (int d = 0; d < 32; ++d) {
                const int c = t * 32 + d;
                k1v = fmaf(Wq[c], gamma[c], k1v);
                k2v = fmaf(Wq[c], beta[c],  k2v);
            }
            ((float*)(ws + WS_K1))[t] = k1v;
            ((float*)(ws + WS_K2))[t] = k2v;
        }
    } else {
        const int ci = t & 15;
        const int kk = t >> 4;
        #pragma unroll
        for (int i = 0; i < 16; ++i) {
            const int k = i * 16 + kk;
            float v;
            if (nt < 16) v = Wk[(size_t)k * C_DIM + nt * 16 + ci] * WSCALE;
            else         v = Wv[(size_t)k * C_DIM + (nt - 16) * 16 + ci] * WSCALE;
            Wl[k * 16 + ci] = v;
        }
    }
    __syncthreads();

    f16x8* __restrict__ WT = (f16x8*)(ws + WS_WT);
    const int lane = t & 63;
    const int l15  = lane & 15;
    const int hi   = lane >> 4;
    for (int kt = (t >> 6); kt < 8; kt += 4) {
        f16x8 frag;
        #pragma unroll
        for (int j = 0; j < 8; ++j)
            frag[j] = (_Float16)Wl[(kt * 32 + hi * 8 + j) * 16 + l15];
        WT[(nt * 8 + kt) * 64 + lane] = frag;
    }
}

// ---------------------------------------------------------------------------
// K1: 32-row tile, 512 threads / 8 waves. Wave w owns 64 output cols:
//   w<4: K cols [w*64, w*64+64)   (n-tiles nt = w*4+j)
//   w>=4: V cols [(w-4)*64, ...)  (n-tiles nt = 16+(w-4)*4+j)
// acc = 2 m x 4 j x f32x4 = 32 VGPR; B-frags double-buffered (static idx).
// Wave 0 also runs the ext tile (nt=32) -> T[r,h], sk, sv via MFMA.
// C never leaves registers.
// ---------------------------------------------------------------------------
__global__ __launch_bounds__(512, 4)
void k1_mfma_ln_reduce(const float* __restrict__ U,
                       const float* __restrict__ gamma,
                       const float* __restrict__ beta,
                       const char* __restrict__ ws_ro,
                       float* __restrict__ part)
{
    __shared__ char lds[19904];
    // A-tile f16 [32][256] swizzled: byte = row*512 + (off ^ ((row&7)<<4)) [0,16384)
    float*  __restrict__ T_lds = (float*)(lds + 16384);   // [32][9] padded
    float*  __restrict__ sk_a  = (float*)(lds + 17536);   // [32]
    float*  __restrict__ sv_a  = (float*)(lds + 17664);   // [32]
    float*  __restrict__ qq    = (float*)(lds + 17792);   // [8][32]
    float*  __restrict__ sr    = (float*)(lds + 18816);   // [8][32]
    float2* __restrict__ DS1   = (float2*)(lds + 19840);  // [8] {D, S1}

    const int t    = threadIdx.x;
    const int lane = t & 63;
    const int w    = t >> 6;
    const int l15  = lane & 15;
    const int rg   = lane >> 4;
    const int bid  = blockIdx.x;           // 1024
    const int b    = bid >> 8;
    const int row0 = (bid & 255) * 32;

    // ---- stage U tile -> f16 swizzled LDS ----
    {
        const float* __restrict__ Ub = U + ((size_t)b * N_DIM + row0) * C_DIM;
        #pragma unroll
        for (int i = 0; i < 2; ++i) {
            const int id = i * 512 + t;
            const int r  = id >> 5;
            const int kc = id & 31;
            const float4* __restrict__ src =
                (const float4*)(Ub + (size_t)r * C_DIM + kc * 8);
            const float4 v0 = src[0];
            const float4 v1 = src[1];
            f16x8 hv;
            hv[0] = (_Float16)v0.x; hv[1] = (_Float16)v0.y;
            hv[2] = (_Float16)v0.z; hv[3] = (_Float16)v0.w;
            hv[4] = (_Float16)v1.x; hv[5] = (_Float16)v1.y;
            hv[6] = (_Float16)v1.z; hv[7] = (_Float16)v1.w;
            *(f16x8*)(lds + r * 512 + ((kc * 16) ^ ((r & 7) << 4))) = hv;
        }
    }
    __syncthreads();

    // ---- MFMA k-loop with double-buffered B-fragments ----
    f32x4 acc[2][4];
    f32x4 acce[2];
    #pragma unroll
    for (int m = 0; m < 2; ++m) {
        #pragma unroll
        for (int j = 0; j < 4; ++j) acc[m][j] = (f32x4)0.0f;
        acce[m] = (f32x4)0.0f;
    }
    {
        const f16x8* __restrict__ WT = (const f16x8*)(ws_ro + WS_WT);
        const int swz = (l15 & 7) << 4;
        const int nt0 = (w < 4) ? (w * 4) : (16 + (w - 4) * 4);
        const int we0 = (w == 0);

        f16x8 bfA[4], bfB[4], beA, beB;
        #pragma unroll
        for (int j = 0; j < 4; ++j) bfA[j] = WT[(size_t)((nt0 + j) * 8 + 0) * 64 + lane];
        if (we0) beA = WT[(size_t)(32 * 8 + 0) * 64 + lane];

        #pragma unroll
        for (int kth = 0; kth < 4; ++kth) {
            const int kt0 = kth * 2;
            const int kt1 = kth * 2 + 1;
            // even step: compute with bfA, prefetch bfB(kt1)
            {
                const int boff = ((kt0 * 64 + rg * 16) ^ swz) + l15 * 512;
                const f16x8 a0 = *(const f16x8*)(lds + boff);
                const f16x8 a1 = *(const f16x8*)(lds + boff + 8192);
                #pragma unroll
                for (int j = 0; j < 4; ++j) bfB[j] = WT[(size_t)((nt0 + j) * 8 + kt1) * 64 + lane];
                if (we0) beB = WT[(size_t)(32 * 8 + kt1) * 64 + lane];
                #pragma unroll
                for (int j = 0; j < 4; ++j) {
                    acc[0][j] = __builtin_amdgcn_mfma_f32_16x16x32_f16(a0, bfA[j], acc[0][j], 0, 0, 0);
                    acc[1][j] = __builtin_amdgcn_mfma_f32_16x16x32_f16(a1, bfA[j], acc[1][j], 0, 0, 0);
                }
                if (we0) {
                    acce[0] = __builtin_amdgcn_mfma_f32_16x16x32_f16(a0, beA, acce[0], 0, 0, 0);
                    acce[1] = __builtin_amdgcn_mfma_f32_16x16x32_f16(a1, beA, acce[1], 0, 0, 0);
                }
            }
            // odd step: compute with bfB, prefetch bfA(kt0+2)
            {
                const int boff = ((kt1 * 64 + rg * 16) ^ swz) + l15 * 512;
                const f16x8 a0 = *(const f16x8*)(lds + boff);
                const f16x8 a1 = *(const f16x8*)(lds + boff + 8192);
                if (kth < 3) {
                    #pragma unroll
                    for (int j = 0; j < 4; ++j) bfA[j] = WT[(size_t)((nt0 + j) * 8 + kt0 + 2) * 64 + lane];
                    if (we0) beA = WT[(size_t)(32 * 8 + kt0 + 2) * 64 + lane];
                }
                #pragma unroll
                for (int j = 0; j < 4; ++j) {
                    acc[0][j] = __builtin_amdgcn_mfma_f32_16x16x32_f16(a0, bfB[j], acc[0][j], 0, 0, 0);
                    acc[1][j] = __builtin_amdgcn_mfma_f32_16x16x32_f16(a1, bfB[j], acc[1][j], 0, 0, 0);
                }
                if (we0) {
                    acce[0] = __builtin_amdgcn_mfma_f32_16x16x32_f16(a0, beB, acce[0], 0, 0, 0);
                    acce[1] = __builtin_amdgcn_mfma_f32_16x16x32_f16(a1, beB, acce[1], 0, 0, 0);
                }
            }
        }
    }

    // ---- wave 0: scatter extra-tile outputs (T, sk, sv) ----
    if (w == 0) {
        #pragma unroll
        for (int m = 0; m < 2; ++m)
            #pragma unroll
            for (int q = 0; q < 4; ++q) {
                const int row = m * 16 + rg * 4 + q;
                const float val = acce[m][q];
                if (l15 < 8)       T_lds[row * 9 + l15] = val * INV_M_SCALE;
                else if (l15 == 8) sk_a[row] = val * INV_SUM_SCALE;
                else if (l15 == 9) sv_a[row] = val * INV_SUM_SCALE;
            }
    }

    // ---- per-row sum of squares of this wave's 64 cols ----
    {
        float qp[8];
        #pragma unroll
        for (int m = 0; m < 2; ++m)
            #pragma unroll
            for (int q = 0; q < 4; ++q) {
                float s = 0.f;
                #pragma unroll
                for (int j = 0; j < 4; ++j) {
                    const float v = acc[m][j][q];
                    s = fmaf(v, v, s);
                }
                qp[m * 4 + q] = s;
            }
        #pragma unroll
        for (int i = 0; i < 8; ++i) {
            #pragma unroll
            for (int msk = 1; msk <= 8; msk <<= 1)
                qp[i] += __shfl_xor(qp[i], msk, 64);
        }
        if (l15 == 0) {
            #pragma unroll
            for (int m = 0; m < 2; ++m)
                #pragma unroll
                for (int q = 0; q < 4; ++q)
                    qq[w * 32 + m * 16 + rg * 4 + q] = qp[m * 4 + q];
        }
    }
    __syncthreads();

    // ---- stats + s[r,h] + D/S1 (lanes 0..31 of wave 0) ----
    if (t < 32) {
        const int r = t;
        const float sk = sk_a[r];
        const float sv = sv_a[r];
        const float qkk = (qq[0 * 32 + r] + qq[1 * 32 + r] +
                           qq[2 * 32 + r] + qq[3 * 32 + r]) * (INV_WSCALE * INV_WSCALE);
        const float qvv = (qq[4 * 32 + r] + qq[5 * 32 + r] +
                           qq[6 * 32 + r] + qq[7 * 32 + r]) * (INV_WSCALE * INV_WSCALE);
        const float muk  = sk * (1.f / 256.f);
        const float vark = qkk * (1.f / 256.f) - muk * muk;
        const float rsk  = 1.0f / sqrtf(vark + LN_EPS);
        const float muv  = sv * (1.f / 256.f);
        const float varv = qvv * (1.f / 256.f) - muv * muv;
        const float rsv  = 1.0f / sqrtf(varv + LN_EPS);
        const float wvr  = muv * rsv;
        const float* __restrict__ K1 = (const float*)(ws_ro + WS_K1);
        const float* __restrict__ K2 = (const float*)(ws_ro + WS_K2);
        #pragma unroll
        for (int h = 0; h < 8; ++h) {
            const float s = fmaf(rsk, T_lds[r * 9 + h] - muk * K1[h], K2[h]);
            sr[h * 32 + r] = s * rsv * INV_WSCALE;
            float d = s * wvr, s1 = s;
            #pragma unroll
            for (int msk = 1; msk <= 16; msk <<= 1) {
                d  += __shfl_xor(d,  msk, 64);
                s1 += __shfl_xor(s1, msk, 64);
            }
            if (r == h) DS1[h] = make_float2(d, s1);
        }
    }
    __syncthreads();

    // ---- V-waves: qk partial for this tile ----
    if (w >= 4) {
        #pragma unroll
        for (int j = 0; j < 4; ++j) {
            const int h = (w - 4) * 2 + (j >> 1);
            float p = 0.f;
            #pragma unroll
            for (int m = 0; m < 2; ++m) {
                const f32x4 s4 = *(const f32x4*)&sr[h * 32 + m * 16 + rg * 4];
                p = fmaf(s4[0], acc[m][j][0], p);
                p = fmaf(s4[1], acc[m][j][1], p);
                p = fmaf(s4[2], acc[m][j][2], p);
                p = fmaf(s4[3], acc[m][j][3], p);
            }
            p += __shfl_xor(p, 16, 64);
            p += __shfl_xor(p, 32, 64);
            if (rg == 0) {
                const int c = (w - 4) * 64 + j * 16 + l15;
                const float2 ds = DS1[h];
                part[(size_t)bid * 256 + c] =
                    fmaf(gamma[c], p - ds.x, beta[c] * ds.y);
            }
        }
    }
}

// ---------------------------------------------------------------------------
// K2: reduce 256 tile-partials per batch -> qk[b][c]
// grid 32: (b = blk>>3, col-group cg = blk&7)
// ---------------------------------------------------------------------------
__global__ void k2_reduce(const float* __restrict__ part, float* __restrict__ qk)
{
    __shared__ float red[8][32];
    const int t   = threadIdx.x;
    const int blk = blockIdx.x;
    const int b   = blk >> 3;
    const int cg  = blk & 7;
    const int c   = cg * 32 + (t & 31);
    const int seg = t >> 5;
    float s = 0.f;
    for (int i = seg * 32; i < seg * 32 + 32; ++i)
        s += part[((size_t)b * 256 + i) * 256 + c];
    red[seg][t & 31] = s;
    __syncthreads();
    if (t < 32) {
        float q = 0.f;
        #pragma unroll
        for (int sgi = 0; sgi < 8; ++sgi) q += red[sgi][t];
        qk[b * 256 + cg * 32 + t] = q;
    }
}

// ---------------------------------------------------------------------------
// K3: out[b,n,e*8+h] = X[b,n] * qk[b,h*32+e] / N
// ---------------------------------------------------------------------------
__global__ __launch_bounds__(256)
void k3_out(const float* __restrict__ X, const float* __restrict__ qk,
            float* __restrict__ out)
{
    __shared__ float qkp[256];
    const int t = threadIdx.x;
    const int bid = blockIdx.x;
    const int b = bid >> 8;
    const int row0 = (bid & 255) * 32;

    {
        const int h = t & 7;
        const int e = t >> 3;
        qkp[t] = qk[b * 256 + h * 32 + e] * (1.0f / (float)N_DIM);
    }
    __syncthreads();

    const int c4 = (t & 63) * 4;
    const float4 q4 = *(const float4*)&qkp[c4];
    const int rl = t >> 6;

    for (int it = 0; it < 8; ++it) {
        const int row = row0 + it * 4 + rl;
        const float x = X[(size_t)b * N_DIM + row];
        float4 o;
        o.x = x * q4.x; o.y = x * q4.y; o.z = x * q4.z; o.w = x * q4.w;
        *(float4*)&out[((size_t)b * N_DIM + row) * C_DIM + c4] = o;
    }
}

// ---------------------------------------------------------------------------
extern "C" void kernel_launch(void* const* d_in, const int* in_sizes, int n_in,
                              void* d_out, int out_size, void* d_ws, size_t ws_size,
                              hipStream_t stream)
{
    const float* U     = (const float*)d_in[0];
    const float* X     = (const float*)d_in[1];
    const float* Wq    = (const float*)d_in[2];
    const float* Wk    = (const float*)d_in[3];
    const float* Wv    = (const float*)d_in[4];
    const float* gamma = (const float*)d_in[5];
    const float* beta  = (const float*)d_in[6];
    float* out = (float*)d_out;

    char* ws = (char*)d_ws;
    float* part = (float*)(ws + WS_PART);
    float* qk   = (float*)(ws + WS_QK);

    k0_pack<<<33, 256, 0, stream>>>(Wq, Wk, Wv, gamma, beta, ws);
    k1_mfma_ln_reduce<<<1024, 512, 0, stream>>>(U, gamma, beta, ws, part);
    k2_reduce<<<32, 256, 0, stream>>>(part, qk);
    k3_out<<<1024, 256, 0, stream>>>(X, qk, out);
}